// Round 15
// baseline (115.803 us; speedup 1.0000x reference)
//
#include <hip/hip_runtime.h>

#define NPIX (128 * 128)
#define CH 64
#define RMID 16
#define KK 9
#define PLANE_B 65536            // bytes per channel plane

typedef float v2f __attribute__((ext_vector_type(2)));

// r22: r16 exact structure + conv1 TRIPLE-buffer.
// r21 post-mortem: half-shuffle taps neutral (113.8 vs 112.5) — the 6
// removed bpermutes were already hidden under wgen; the 6 added loads
// cancel. Shuffle path is NOT critical. Reverted to r16 full-shuffle taps.
// Remaining modeled stall: conv1 ladder VMWAIT(8) with only 16 loads in
// flight exposes a fraction of L2 latency 8 times/wave. r22 deepens to
// 3 octet buffers / 24 in flight / steady VMWAIT(16): each wait needs only
// the oldest third landed. +16 VGPR, no occupancy effect at 4 waves/SIMD.
// Ledger: prologue 30 (6 taps + 24); W16 retires taps+oct0; then 1 octet
// per step; tail W16, W8, W0. Group ladder identical to r16 (VMWAIT(6),
// 12 shuffles/group, final VMWAIT(2)).
#define ASM_LOAD2(dst, base, voff) \
    asm volatile("global_load_dwordx2 %0, %1, %2" \
                 : "=v"(dst) : "v"((uint32_t)(voff)), "s"(base))

#define VMWAIT(N) do { \
    asm volatile("s_waitcnt vmcnt(" #N ")" ::: "memory"); \
    __builtin_amdgcn_sched_barrier(0); \
} while (0)

#define ISSUE8(B, base, oct) do { \
    const uint32_t c0 = (uint32_t)pb0 + (uint32_t)((oct) * 8) * 65536u; \
    ASM_LOAD2(B##0, base, c0); \
    ASM_LOAD2(B##1, base, c0 + 1u * 65536u); \
    ASM_LOAD2(B##2, base, c0 + 2u * 65536u); \
    ASM_LOAD2(B##3, base, c0 + 3u * 65536u); \
    ASM_LOAD2(B##4, base, c0 + 4u * 65536u); \
    ASM_LOAD2(B##5, base, c0 + 5u * 65536u); \
    ASM_LOAD2(B##6, base, c0 + 6u * 65536u); \
    ASM_LOAD2(B##7, base, c0 + 7u * 65536u); \
} while (0)

#define FMA8(xvreg, ch) do { \
    _Pragma("unroll") \
    for (int r = 0; r < RMID; ++r) { \
        const float w = w1[r * CH + (ch)]; \
        v2f wv; wv.x = w; wv.y = w; \
        t2[r] = __builtin_elementwise_fma(wv, (xvreg), t2[r]); \
    } \
} while (0)

#define CONSUME8(B, oct) do { \
    FMA8(B##0, (oct) * 8 + 0); \
    FMA8(B##1, (oct) * 8 + 1); \
    FMA8(B##2, (oct) * 8 + 2); \
    FMA8(B##3, (oct) * 8 + 3); \
    FMA8(B##4, (oct) * 8 + 4); \
    FMA8(B##5, (oct) * 8 + 5); \
    FMA8(B##6, (oct) * 8 + 6); \
    FMA8(B##7, (oct) * 8 + 7); \
} while (0)

#define ISSUE_TAPS(B, gg) do { \
    const uint32_t q0 = (uint32_t)pb0 + (uint32_t)(2 * (gg)) * 65536u; \
    const uint32_t q1 = q0 + 65536u; \
    ASM_LOAD2(B##A0, xbc, q0 + (uint32_t)ro0); \
    ASM_LOAD2(B##A1, xbc, q0); \
    ASM_LOAD2(B##A2, xbc, q0 + (uint32_t)ro2); \
    ASM_LOAD2(B##E0, xbc, q1 + (uint32_t)ro0); \
    ASM_LOAD2(B##E1, xbc, q1); \
    ASM_LOAD2(B##E2, xbc, q1 + (uint32_t)ro2); \
} while (0)

#define PRELU_T2() do { \
    const float a = prelu_a[0]; \
    v2f av; av.x = a; av.y = a; \
    v2f z;  z.x = 0.f; z.y = 0.f; \
    _Pragma("unroll") \
    for (int r = 0; r < RMID; ++r) { \
        const v2f pos = __builtin_elementwise_max(t2[r], z); \
        const v2f neg = __builtin_elementwise_min(t2[r], z); \
        t2[r] = __builtin_elementwise_fma(av, neg, pos); \
    } \
} while (0)

// triple-buffered: 24 x-loads in flight, steady VMWAIT(16)
#define CONV1_LADDER3() do { \
    VMWAIT(16); CONSUME8(xA, 0); ISSUE8(xA, xbc, 3); \
    VMWAIT(16); CONSUME8(xB, 1); ISSUE8(xB, xbc, 4); \
    VMWAIT(16); CONSUME8(xC, 2); ISSUE8(xC, xbc, 5); \
    VMWAIT(16); CONSUME8(xA, 3); ISSUE8(xA, xbc, 6); \
    VMWAIT(16); CONSUME8(xB, 4); ISSUE8(xB, xbc, 7); \
    VMWAIT(16); CONSUME8(xC, 5); \
    VMWAIT(8);  CONSUME8(xA, 6); \
    VMWAIT(0);  CONSUME8(xB, 7); \
} while (0)

__device__ __forceinline__ void group_tail(
    int g, v2f tA0, v2f tA1, v2f tA2, v2f tE0, v2f tE1, v2f tE2,
    float mL, float mR, v2f rm0v, v2f rm2v,
    const v2f (&t2)[RMID], const float* __restrict__ w2,
    const float* __restrict__ b2, char* obc, int pb0)
{
    const v2f A0 = tA0 * rm0v;
    const v2f A1 = tA1;
    const v2f A2 = tA2 * rm2v;
    const v2f E0 = tE0 * rm0v;
    const v2f E1 = tE1;
    const v2f E2 = tE2 * rm2v;

    const float lA0 = __shfl_up(A0.y, 1), rA0 = __shfl_down(A0.x, 1);
    const float lA1 = __shfl_up(A1.y, 1), rA1 = __shfl_down(A1.x, 1);
    const float lA2 = __shfl_up(A2.y, 1), rA2 = __shfl_down(A2.x, 1);
    const float lE0 = __shfl_up(E0.y, 1), rE0 = __shfl_down(E0.x, 1);
    const float lE1 = __shfl_up(E1.y, 1), rE1 = __shfl_down(E1.x, 1);
    const float lE2 = __shfl_up(E2.y, 1), rE2 = __shfl_down(E2.x, 1);

    v2f oA; oA.x = 0.f; oA.y = 0.f;
    v2f oB = oA;
#pragma unroll
    for (int k = 0; k < KK; ++k) {
        const float* w2r = w2 + (g * KK + k) * RMID;  // uniform -> s_load
        const float bb = b2[g * KK + k];
        v2f acc; acc.x = bb; acc.y = bb;
#pragma unroll
        for (int r = 0; r < RMID; ++r) {
            const float w = w2r[r];
            v2f wv; wv.x = w; wv.y = w;
            acc = __builtin_elementwise_fma(wv, t2[r], acc);
        }
        if (k == 0 || k == 3 || k == 6) acc.x *= mL;   // left tap of px0
        if (k == 2 || k == 5 || k == 8) acc.y *= mR;   // right tap of px1

        const v2f Ar = (k < 3) ? A0 : (k < 6) ? A1 : A2;
        const v2f Er = (k < 3) ? E0 : (k < 6) ? E1 : E2;
        const float lA = (k < 3) ? lA0 : (k < 6) ? lA1 : lA2;
        const float rA = (k < 3) ? rA0 : (k < 6) ? rA1 : rA2;
        const float lE = (k < 3) ? lE0 : (k < 6) ? lE1 : lE2;
        const float rE = (k < 3) ? rE0 : (k < 6) ? rE1 : rE2;

        v2f tpA, tpE;
        if (k % 3 == 0)      { tpA.x = lA;   tpA.y = Ar.x;
                               tpE.x = lE;   tpE.y = Er.x; }
        else if (k % 3 == 1) { tpA = Ar;     tpE = Er;     }
        else                 { tpA.x = Ar.y; tpA.y = rA;
                               tpE.x = Er.y; tpE.y = rE;   }
        oA = __builtin_elementwise_fma(acc, tpA, oA);
        oB = __builtin_elementwise_fma(acc, tpE, oB);
    }

    __builtin_nontemporal_store(oA, (v2f*)(obc + (size_t)(2 * g)     * PLANE_B + pb0));
    __builtin_nontemporal_store(oB, (v2f*)(obc + (size_t)(2 * g + 1) * PLANE_B + pb0));
}

__global__ __launch_bounds__(256, 2) void invol_fused(
    const float* __restrict__ x,
    const float* __restrict__ w1,
    const float* __restrict__ b1,
    const float* __restrict__ prelu_a,
    const float* __restrict__ w2,
    const float* __restrict__ b2,
    float* __restrict__ out)
{
    const int c    = threadIdx.x & 63;    // column-pair id (cols 2c, 2c+1)
    const int rsub = threadIdx.x >> 6;    // row within strip, wave-uniform

    const int L     = blockIdx.x;         // 0..1023
    const int bq    = L & 7;              // batch == XCD pin
    const int go    = (L >> 3) & 3;       // group-octet (consecutive per XCD)
    const int strip = L >> 5;             // 0..31 (4 rows)

    const int hq  = 4 * strip + rsub;
    const int p0  = hq * 128 + 2 * c;
    const int pb0 = 4 * p0;

    const char* xbc = (const char*)(x + (size_t)bq * CH * NPIX);

    const float rm0 = (hq > 0)   ? 1.f : 0.f;
    const float rm2 = (hq < 127) ? 1.f : 0.f;
    const float mL  = (c > 0)    ? 1.f : 0.f;
    const float mR  = (c < 63)   ? 1.f : 0.f;
    const int   ro0 = (hq > 0)   ? -512 : 0;
    const int   ro2 = (hq < 127) ?  512 : 0;

    v2f xA0, xA1, xA2, xA3, xA4, xA5, xA6, xA7;
    v2f xB0, xB1, xB2, xB3, xB4, xB5, xB6, xB7;
    v2f xC0, xC1, xC2, xC3, xC4, xC5, xC6, xC7;
    v2f taA0, taA1, taA2, taE0, taE1, taE2;
    v2f tbA0, tbA1, tbA2, tbE0, tbE1, tbE2;

    const int g0 = 8 * go;
    ISSUE_TAPS(ta, g0 + 0);
    ISSUE8(xA, xbc, 0);
    ISSUE8(xB, xbc, 1);
    ISSUE8(xC, xbc, 2);

    v2f t2[RMID];
#pragma unroll
    for (int r = 0; r < RMID; ++r) {
        const float b = b1[r];
        t2[r].x = b; t2[r].y = b;
    }

    CONV1_LADDER3();
    PRELU_T2();

    v2f rm0v; rm0v.x = rm0; rm0v.y = rm0;
    v2f rm2v; rm2v.x = rm2; rm2v.y = rm2;
    char* obc = (char*)(out + (size_t)bq * CH * NPIX);

    ISSUE_TAPS(tb, g0 + 1); VMWAIT(6);
    group_tail(g0 + 0, taA0, taA1, taA2, taE0, taE1, taE2, mL, mR, rm0v, rm2v, t2, w2, b2, obc, pb0);
    ISSUE_TAPS(ta, g0 + 2); VMWAIT(6);
    group_tail(g0 + 1, tbA0, tbA1, tbA2, tbE0, tbE1, tbE2, mL, mR, rm0v, rm2v, t2, w2, b2, obc, pb0);
    ISSUE_TAPS(tb, g0 + 3); VMWAIT(6);
    group_tail(g0 + 2, taA0, taA1, taA2, taE0, taE1, taE2, mL, mR, rm0v, rm2v, t2, w2, b2, obc, pb0);
    ISSUE_TAPS(ta, g0 + 4); VMWAIT(6);
    group_tail(g0 + 3, tbA0, tbA1, tbA2, tbE0, tbE1, tbE2, mL, mR, rm0v, rm2v, t2, w2, b2, obc, pb0);
    ISSUE_TAPS(tb, g0 + 5); VMWAIT(6);
    group_tail(g0 + 4, taA0, taA1, taA2, taE0, taE1, taE2, mL, mR, rm0v, rm2v, t2, w2, b2, obc, pb0);
    ISSUE_TAPS(ta, g0 + 6); VMWAIT(6);
    group_tail(g0 + 5, tbA0, tbA1, tbA2, tbE0, tbE1, tbE2, mL, mR, rm0v, rm2v, t2, w2, b2, obc, pb0);
    ISSUE_TAPS(tb, g0 + 7); VMWAIT(6);
    group_tail(g0 + 6, taA0, taA1, taA2, taE0, taE1, taE2, mL, mR, rm0v, rm2v, t2, w2, b2, obc, pb0);
    VMWAIT(2);   // retires g7 taps (oldest); leaves only g6 stores
    group_tail(g0 + 7, tbA0, tbA1, tbA2, tbE0, tbE1, tbE2, mL, mR, rm0v, rm2v, t2, w2, b2, obc, pb0);
}

extern "C" void kernel_launch(void* const* d_in, const int* in_sizes, int n_in,
                              void* d_out, int out_size, void* d_ws, size_t ws_size,
                              hipStream_t stream)
{
    const float* x  = (const float*)d_in[0];
    const float* w1 = (const float*)d_in[1];
    const float* b1 = (const float*)d_in[2];
    const float* pa = (const float*)d_in[3];
    const float* w2 = (const float*)d_in[4];
    const float* b2 = (const float*)d_in[5];
    float* out = (float*)d_out;

    hipLaunchKernelGGL(invol_fused, dim3(1024), dim3(256), 0, stream,
                       x, w1, b1, pa, w2, b2, out);
}

// Round 16
// 112.469 us; speedup vs baseline: 1.0296x; 1.0296x over previous
//
#include <hip/hip_runtime.h>

#define NPIX (128 * 128)
#define CH 64
#define RMID 16
#define KK 9
#define PLANE_B 65536            // bytes per channel plane

typedef float v2f __attribute__((ext_vector_type(2)));

// r23 = r16 revert (final). Best measured: bench 112.5us, kernel ~38-41us.
// Session ledger: the ONE big win was inline-asm global loads + counted
// s_waitcnt vmcnt(N) batching (r16: 52.5 -> ~40us kernel) — the compiler's
// allocator/scheduler could not be coaxed into MLP>1 by any source-level or
// sched_barrier means (r8-r15: always sinks loads to uses at ~52 VGPR).
// All other levers tested and rejected: TLP x2 (r11 -), TLP /2 (r18 -),
// conv1 dedup two-phase (r17 -) and in-kernel (r18 -), half-shuffle taps
// (r21 0), conv1 triple-buffer (r22 -). Residual: VALUBusy ~44%, HBM 16%,
// 0 bank conflicts, no spill — a latency local optimum whose remaining
// stall sources (SMEM w1/w2 streaming, bpermute lgkm, vmem tails) are each
// below bench noise through the ~71us harness floor.
// Structure: grid 1024 = 8 bq (XCD pin, L&7) x 4 group-octets x 32 strips;
// block 256 = 4 rows x 64 col-pairs; wave = one image row. Conv1: 8x8-load
// asm batches, double-buffered, steady vmcnt(8). Taps: 6-load batches one
// group ahead, vmcnt(6); final vmcnt(2). Every vmcnt followed by
// sched_barrier(0) (rule #18). PReLU in-reg; wgen+combine fused per-k;
// nontemporal stores.
#define ASM_LOAD2(dst, base, voff) \
    asm volatile("global_load_dwordx2 %0, %1, %2" \
                 : "=v"(dst) : "v"((uint32_t)(voff)), "s"(base))

#define VMWAIT(N) do { \
    asm volatile("s_waitcnt vmcnt(" #N ")" ::: "memory"); \
    __builtin_amdgcn_sched_barrier(0); \
} while (0)

#define ISSUE8(B, base, oct) do { \
    const uint32_t c0 = (uint32_t)pb0 + (uint32_t)((oct) * 8) * 65536u; \
    ASM_LOAD2(B##0, base, c0); \
    ASM_LOAD2(B##1, base, c0 + 1u * 65536u); \
    ASM_LOAD2(B##2, base, c0 + 2u * 65536u); \
    ASM_LOAD2(B##3, base, c0 + 3u * 65536u); \
    ASM_LOAD2(B##4, base, c0 + 4u * 65536u); \
    ASM_LOAD2(B##5, base, c0 + 5u * 65536u); \
    ASM_LOAD2(B##6, base, c0 + 6u * 65536u); \
    ASM_LOAD2(B##7, base, c0 + 7u * 65536u); \
} while (0)

#define FMA8(xvreg, ch) do { \
    _Pragma("unroll") \
    for (int r = 0; r < RMID; ++r) { \
        const float w = w1[r * CH + (ch)]; \
        v2f wv; wv.x = w; wv.y = w; \
        t2[r] = __builtin_elementwise_fma(wv, (xvreg), t2[r]); \
    } \
} while (0)

#define CONSUME8(B, oct) do { \
    FMA8(B##0, (oct) * 8 + 0); \
    FMA8(B##1, (oct) * 8 + 1); \
    FMA8(B##2, (oct) * 8 + 2); \
    FMA8(B##3, (oct) * 8 + 3); \
    FMA8(B##4, (oct) * 8 + 4); \
    FMA8(B##5, (oct) * 8 + 5); \
    FMA8(B##6, (oct) * 8 + 6); \
    FMA8(B##7, (oct) * 8 + 7); \
} while (0)

#define ISSUE_TAPS(B, gg) do { \
    const uint32_t q0 = (uint32_t)pb0 + (uint32_t)(2 * (gg)) * 65536u; \
    const uint32_t q1 = q0 + 65536u; \
    ASM_LOAD2(B##A0, xbc, q0 + (uint32_t)ro0); \
    ASM_LOAD2(B##A1, xbc, q0); \
    ASM_LOAD2(B##A2, xbc, q0 + (uint32_t)ro2); \
    ASM_LOAD2(B##E0, xbc, q1 + (uint32_t)ro0); \
    ASM_LOAD2(B##E1, xbc, q1); \
    ASM_LOAD2(B##E2, xbc, q1 + (uint32_t)ro2); \
} while (0)

#define PRELU_T2() do { \
    const float a = prelu_a[0]; \
    v2f av; av.x = a; av.y = a; \
    v2f z;  z.x = 0.f; z.y = 0.f; \
    _Pragma("unroll") \
    for (int r = 0; r < RMID; ++r) { \
        const v2f pos = __builtin_elementwise_max(t2[r], z); \
        const v2f neg = __builtin_elementwise_min(t2[r], z); \
        t2[r] = __builtin_elementwise_fma(av, neg, pos); \
    } \
} while (0)

#define CONV1_LADDER() do { \
    VMWAIT(8);  CONSUME8(xA, 0); ISSUE8(xA, xbc, 2); \
    VMWAIT(8);  CONSUME8(xB, 1); ISSUE8(xB, xbc, 3); \
    VMWAIT(8);  CONSUME8(xA, 2); ISSUE8(xA, xbc, 4); \
    VMWAIT(8);  CONSUME8(xB, 3); ISSUE8(xB, xbc, 5); \
    VMWAIT(8);  CONSUME8(xA, 4); ISSUE8(xA, xbc, 6); \
    VMWAIT(8);  CONSUME8(xB, 5); ISSUE8(xB, xbc, 7); \
    VMWAIT(8);  CONSUME8(xA, 6); \
    VMWAIT(0);  CONSUME8(xB, 7); \
} while (0)

__device__ __forceinline__ void group_tail(
    int g, v2f tA0, v2f tA1, v2f tA2, v2f tE0, v2f tE1, v2f tE2,
    float mL, float mR, v2f rm0v, v2f rm2v,
    const v2f (&t2)[RMID], const float* __restrict__ w2,
    const float* __restrict__ b2, char* obc, int pb0)
{
    const v2f A0 = tA0 * rm0v;
    const v2f A1 = tA1;
    const v2f A2 = tA2 * rm2v;
    const v2f E0 = tE0 * rm0v;
    const v2f E1 = tE1;
    const v2f E2 = tE2 * rm2v;

    const float lA0 = __shfl_up(A0.y, 1), rA0 = __shfl_down(A0.x, 1);
    const float lA1 = __shfl_up(A1.y, 1), rA1 = __shfl_down(A1.x, 1);
    const float lA2 = __shfl_up(A2.y, 1), rA2 = __shfl_down(A2.x, 1);
    const float lE0 = __shfl_up(E0.y, 1), rE0 = __shfl_down(E0.x, 1);
    const float lE1 = __shfl_up(E1.y, 1), rE1 = __shfl_down(E1.x, 1);
    const float lE2 = __shfl_up(E2.y, 1), rE2 = __shfl_down(E2.x, 1);

    v2f oA; oA.x = 0.f; oA.y = 0.f;
    v2f oB = oA;
#pragma unroll
    for (int k = 0; k < KK; ++k) {
        const float* w2r = w2 + (g * KK + k) * RMID;  // uniform -> s_load
        const float bb = b2[g * KK + k];
        v2f acc; acc.x = bb; acc.y = bb;
#pragma unroll
        for (int r = 0; r < RMID; ++r) {
            const float w = w2r[r];
            v2f wv; wv.x = w; wv.y = w;
            acc = __builtin_elementwise_fma(wv, t2[r], acc);
        }
        if (k == 0 || k == 3 || k == 6) acc.x *= mL;   // left tap of px0
        if (k == 2 || k == 5 || k == 8) acc.y *= mR;   // right tap of px1

        const v2f Ar = (k < 3) ? A0 : (k < 6) ? A1 : A2;
        const v2f Er = (k < 3) ? E0 : (k < 6) ? E1 : E2;
        const float lA = (k < 3) ? lA0 : (k < 6) ? lA1 : lA2;
        const float rA = (k < 3) ? rA0 : (k < 6) ? rA1 : rA2;
        const float lE = (k < 3) ? lE0 : (k < 6) ? lE1 : lE2;
        const float rE = (k < 3) ? rE0 : (k < 6) ? rE1 : rE2;

        v2f tpA, tpE;
        if (k % 3 == 0)      { tpA.x = lA;   tpA.y = Ar.x;
                               tpE.x = lE;   tpE.y = Er.x; }
        else if (k % 3 == 1) { tpA = Ar;     tpE = Er;     }
        else                 { tpA.x = Ar.y; tpA.y = rA;
                               tpE.x = Er.y; tpE.y = rE;   }
        oA = __builtin_elementwise_fma(acc, tpA, oA);
        oB = __builtin_elementwise_fma(acc, tpE, oB);
    }

    __builtin_nontemporal_store(oA, (v2f*)(obc + (size_t)(2 * g)     * PLANE_B + pb0));
    __builtin_nontemporal_store(oB, (v2f*)(obc + (size_t)(2 * g + 1) * PLANE_B + pb0));
}

__global__ __launch_bounds__(256, 2) void invol_fused(
    const float* __restrict__ x,
    const float* __restrict__ w1,
    const float* __restrict__ b1,
    const float* __restrict__ prelu_a,
    const float* __restrict__ w2,
    const float* __restrict__ b2,
    float* __restrict__ out)
{
    const int c    = threadIdx.x & 63;    // column-pair id (cols 2c, 2c+1)
    const int rsub = threadIdx.x >> 6;    // row within strip, wave-uniform

    const int L     = blockIdx.x;         // 0..1023
    const int bq    = L & 7;              // batch == XCD pin
    const int go    = (L >> 3) & 3;       // group-octet (consecutive per XCD)
    const int strip = L >> 5;             // 0..31 (4 rows)

    const int hq  = 4 * strip + rsub;
    const int p0  = hq * 128 + 2 * c;
    const int pb0 = 4 * p0;

    const char* xbc = (const char*)(x + (size_t)bq * CH * NPIX);

    const float rm0 = (hq > 0)   ? 1.f : 0.f;
    const float rm2 = (hq < 127) ? 1.f : 0.f;
    const float mL  = (c > 0)    ? 1.f : 0.f;
    const float mR  = (c < 63)   ? 1.f : 0.f;
    const int   ro0 = (hq > 0)   ? -512 : 0;
    const int   ro2 = (hq < 127) ?  512 : 0;

    v2f xA0, xA1, xA2, xA3, xA4, xA5, xA6, xA7;
    v2f xB0, xB1, xB2, xB3, xB4, xB5, xB6, xB7;
    v2f taA0, taA1, taA2, taE0, taE1, taE2;
    v2f tbA0, tbA1, tbA2, tbE0, tbE1, tbE2;

    const int g0 = 8 * go;
    ISSUE_TAPS(ta, g0 + 0);
    ISSUE8(xA, xbc, 0);
    ISSUE8(xB, xbc, 1);

    v2f t2[RMID];
#pragma unroll
    for (int r = 0; r < RMID; ++r) {
        const float b = b1[r];
        t2[r].x = b; t2[r].y = b;
    }

    CONV1_LADDER();
    PRELU_T2();

    v2f rm0v; rm0v.x = rm0; rm0v.y = rm0;
    v2f rm2v; rm2v.x = rm2; rm2v.y = rm2;
    char* obc = (char*)(out + (size_t)bq * CH * NPIX);

    ISSUE_TAPS(tb, g0 + 1); VMWAIT(6);
    group_tail(g0 + 0, taA0, taA1, taA2, taE0, taE1, taE2, mL, mR, rm0v, rm2v, t2, w2, b2, obc, pb0);
    ISSUE_TAPS(ta, g0 + 2); VMWAIT(6);
    group_tail(g0 + 1, tbA0, tbA1, tbA2, tbE0, tbE1, tbE2, mL, mR, rm0v, rm2v, t2, w2, b2, obc, pb0);
    ISSUE_TAPS(tb, g0 + 3); VMWAIT(6);
    group_tail(g0 + 2, taA0, taA1, taA2, taE0, taE1, taE2, mL, mR, rm0v, rm2v, t2, w2, b2, obc, pb0);
    ISSUE_TAPS(ta, g0 + 4); VMWAIT(6);
    group_tail(g0 + 3, tbA0, tbA1, tbA2, tbE0, tbE1, tbE2, mL, mR, rm0v, rm2v, t2, w2, b2, obc, pb0);
    ISSUE_TAPS(tb, g0 + 5); VMWAIT(6);
    group_tail(g0 + 4, taA0, taA1, taA2, taE0, taE1, taE2, mL, mR, rm0v, rm2v, t2, w2, b2, obc, pb0);
    ISSUE_TAPS(ta, g0 + 6); VMWAIT(6);
    group_tail(g0 + 5, tbA0, tbA1, tbA2, tbE0, tbE1, tbE2, mL, mR, rm0v, rm2v, t2, w2, b2, obc, pb0);
    ISSUE_TAPS(tb, g0 + 7); VMWAIT(6);
    group_tail(g0 + 6, taA0, taA1, taA2, taE0, taE1, taE2, mL, mR, rm0v, rm2v, t2, w2, b2, obc, pb0);
    VMWAIT(2);  // retires g7 taps (oldest); leaves only g6 stores
    group_tail(g0 + 7, tbA0, tbA1, tbA2, tbE0, tbE1, tbE2, mL, mR, rm0v, rm2v, t2, w2, b2, obc, pb0);
}

extern "C" void kernel_launch(void* const* d_in, const int* in_sizes, int n_in,
                              void* d_out, int out_size, void* d_ws, size_t ws_size,
                              hipStream_t stream)
{
    const float* x  = (const float*)d_in[0];
    const float* w1 = (const float*)d_in[1];
    const float* b1 = (const float*)d_in[2];
    const float* pa = (const float*)d_in[3];
    const float* w2 = (const float*)d_in[4];
    const float* b2 = (const float*)d_in[5];
    float* out = (float*)d_out;

    hipLaunchKernelGGL(invol_fused, dim3(1024), dim3(256), 0, stream,
                       x, w1, b1, pa, w2, b2, out);
}